// Round 8
// baseline (3893.603 us; speedup 1.0000x reference)
//
#include <hip/hip_runtime.h>
#include <hip/hip_cooperative_groups.h>

// Tree-GRU encoder, round 8.
//  - xg = Xc @ Wx^T precomputed per pass (dense GEMM); recurrent loop is h-side
//    only (3 gates, acc 96 AGPR) -> register budget allows 2-deep prefetch.
//  - LDS double-buffered (Ah 2x32K + B 2x24K = 112KB), ONE barrier per K-chunk,
//    2-chunk-deep register pipeline covers LLC/fabric latency.
//  - XCD-correct mapping: rp=bi&31, cg=bi>>5 -> the 8 col-group blocks sharing
//    an A-tile have identical bi%8 -> same XCD L2 (A fetched once per XCD).
//  - custom epoch grid-barrier (agent-scope atomics + fences + s_sleep spin)
//    replaces cooperative grid.sync(); sequential DT/TD passes share one xg.
//  - rotated chunk order ends at chunk cg -> epilogue hprev comes from LDS.
//  - finalize (compact->out, nontemporal) fused into pass-1 tail.
//
// ws (~208 MB): wt 4x[1536][512]bf16 | Xc[NG][512] | xg[NG][1536] |
//   Hdt/Htd[NG][512] (aliased across passes) | zrow | Hfd[NG][512] |
//   sched/meta/gidx/pslot | bar[128]

#define NL 256
#define NB 128
#define NH 512
#define NG (NB * NL)
#define NBLK 256

typedef short short8 __attribute__((ext_vector_type(8)));
typedef float f32x4 __attribute__((ext_vector_type(4)));
typedef float f32x16 __attribute__((ext_vector_type(16)));

__device__ __forceinline__ float bf2f(unsigned short u) {
  union { unsigned int i; float f; } c; c.i = ((unsigned int)u) << 16; return c.f;
}
__device__ __forceinline__ unsigned short f2bf(float f) {
  union { float f; unsigned int i; } c; c.f = f;
  return (unsigned short)((c.i + 0x7FFFu + ((c.i >> 16) & 1u)) >> 16);  // RNE
}
__device__ __forceinline__ short8 pk_bf16(f32x4 a, f32x4 b) {
  union { unsigned int u[4]; short8 s; } r;
  asm("v_cvt_pk_bf16_f32 %0, %1, %2" : "=v"(r.u[0]) : "v"(a[0]), "v"(a[1]));
  asm("v_cvt_pk_bf16_f32 %0, %1, %2" : "=v"(r.u[1]) : "v"(a[2]), "v"(a[3]));
  asm("v_cvt_pk_bf16_f32 %0, %1, %2" : "=v"(r.u[2]) : "v"(b[0]), "v"(b[1]));
  asm("v_cvt_pk_bf16_f32 %0, %1, %2" : "=v"(r.u[3]) : "v"(b[2]), "v"(b[3]));
  return r.s;
}
__device__ __forceinline__ void atom_pk_bf16(unsigned short* p, unsigned int ud) {
  asm volatile("global_atomic_pk_add_bf16 %0, %1, off" :: "v"((void*)p), "v"(ud) : "memory");
}

// epoch-counting grid barrier: release fence -> arrive -> last sets go -> spin
__device__ __forceinline__ void grid_bar(unsigned int* bar, unsigned int epoch) {
  __builtin_amdgcn_fence(__ATOMIC_RELEASE, "agent");
  __syncthreads();
  if (threadIdx.x == 0) {
    unsigned int arr = __hip_atomic_fetch_add(&bar[0], 1u, __ATOMIC_RELAXED,
                                              __HIP_MEMORY_SCOPE_AGENT) + 1u;
    if (arr == (unsigned int)NBLK * epoch) {
      __hip_atomic_store(&bar[32], epoch, __ATOMIC_RELAXED, __HIP_MEMORY_SCOPE_AGENT);
    } else {
      unsigned int g;
      do {
        __builtin_amdgcn_s_sleep(2);
        g = __hip_atomic_load(&bar[32], __ATOMIC_RELAXED, __HIP_MEMORY_SCOPE_AGENT);
      } while (g < epoch);
    }
  }
  __syncthreads();
  __builtin_amdgcn_fence(__ATOMIC_ACQUIRE, "agent");
}

// ---- prep: 4 weight matrices [512][1536] f32 -> transposed [1536][512] bf16 ----
__global__ void prep_wt4(const float* __restrict__ w0, const float* __restrict__ w1,
                         const float* __restrict__ w2, const float* __restrict__ w3,
                         unsigned short* __restrict__ wt) {
  __shared__ float t[32][33];
  const float* w = blockIdx.z == 0 ? w0 : blockIdx.z == 1 ? w1 : blockIdx.z == 2 ? w2 : w3;
  unsigned short* dst = wt + (size_t)blockIdx.z * 1536 * 512;
  int n0 = blockIdx.x * 32, k0 = blockIdx.y * 32;
  int tx = threadIdx.x & 31, ty = threadIdx.x >> 5;
  #pragma unroll
  for (int i = 0; i < 4; ++i)
    t[ty + 8 * i][tx] = w[(size_t)(k0 + ty + 8 * i) * 1536 + n0 + tx];
  __syncthreads();
  #pragma unroll
  for (int i = 0; i < 4; ++i)
    dst[(size_t)(n0 + ty + 8 * i) * 512 + k0 + tx] = f2bf(t[tx][ty + 8 * i]);
}

// ---- prep: depths, level buckets, slots, parent slots (1 block, 256 thr) ----
__global__ void prep_sched(const int* __restrict__ td_pidx,
                           const float* __restrict__ td_pval,
                           int* __restrict__ sched, int* __restrict__ meta,
                           int* __restrict__ gidx, int* __restrict__ pslot) {
  __shared__ unsigned char dep[NB][NL];
  __shared__ unsigned short cnb[NB][256];
  __shared__ int cnt[256];
  __shared__ int off[257];
  __shared__ int dmax_s;
  const int tid = threadIdx.x;
  for (int j = tid; j < NB * 256; j += 256) ((unsigned short*)cnb)[j] = 0;
  if (tid == 0) dmax_s = 0;
  __syncthreads();
  if (tid < NB) {
    int b = tid, lmax = 0;
    for (int i = 0; i < NL; ++i) {
      float pv = td_pval[i * NB + b];
      int pi = td_pidx[i * NB + b];
      int d = (pv != 0.f) ? (int)dep[b][pi] + 1 : 0;   // head[i] < i
      dep[b][i] = (unsigned char)d;
      cnb[b][d]++;
      lmax = max(lmax, d);
    }
    atomicMax(&dmax_s, lmax);
  }
  __syncthreads();
  {
    int s = 0;
    for (int b = 0; b < NB; ++b) s += cnb[b][tid];
    cnt[tid] = s;
  }
  __syncthreads();
  if (tid == 0) {
    int s = 0;
    for (int d = 0; d < 256; ++d) { off[d] = s; s += cnt[d]; }
    off[256] = s;
  }
  __syncthreads();
  {
    int run = off[tid];
    for (int b = 0; b < NB; ++b) {
      int t = cnb[b][tid];
      cnb[b][tid] = (unsigned short)run;
      run += t;
    }
  }
  __syncthreads();
  if (tid < NB) {
    int b = tid;
    for (int i = 0; i < NL; ++i) {
      float pv = td_pval[i * NB + b];
      int pi = td_pidx[i * NB + b];
      int d = dep[b][i];
      int g = cnb[b][d]++;
      sched[g] = (b << 8) | i;
      gidx[b * NL + i] = g;
      pslot[g] = (pv != 0.f) ? gidx[b * NL + pi] : -1;
    }
  }
  if (tid == 0) meta[0] = dmax_s;
  __syncthreads();
  meta[1 + tid] = off[tid];
  meta[257 + tid] = cnt[tid];
}

// ---- prep: gather emb rows into slot order, f32 -> bf16 ----
__global__ void prep_xc(const float* __restrict__ emb, const int* __restrict__ sched,
                        unsigned short* __restrict__ Xc) {
  int g = blockIdx.x * 4 + (threadIdx.x >> 6);
  int lane = threadIdx.x & 63;
  int e = sched[g];
  int b = e >> 8, node = e & 255;
  const float* src = emb + ((size_t)node * NB + b) * 512 + lane * 8;
  f32x4 v0 = *(const f32x4*)src;
  f32x4 v1 = *(const f32x4*)(src + 4);
  *(short8*)(Xc + (size_t)g * 512 + lane * 8) = pk_bf16(v0, v1);
}

// ---- dense GEMM: xg[NG][1536] = Xc[NG][512] @ W[1536][512]^T (bf16) ----
__launch_bounds__(256, 2)
__global__ void gemm_xg(const unsigned short* __restrict__ Xc,
                        const unsigned short* __restrict__ W,
                        unsigned short* __restrict__ xg) {
  __shared__ unsigned char lds[32768];
  const int tid = threadIdx.x;
  const int m0 = blockIdx.x * 128;
  const int n0 = blockIdx.y * 128;
  const int w = tid >> 6, l = tid & 63;
  const int lm = l & 15, kg = l >> 4;
  const int wr = (w & 1) * 64, wc = (w >> 1) * 64;
  const int srow = tid >> 3, sslot = tid & 7;
  const int dsw = ((sslot ^ (srow & 7)) << 4);
  const unsigned short* asrc = Xc + (size_t)(m0 + srow) * 512 + sslot * 8;
  const unsigned short* bsrc = W + (size_t)(n0 + srow) * 512 + sslot * 8;
  unsigned char* Ab = lds;
  unsigned char* Bb = lds + 16384;
  short8 ra[4], rb[4];
  #pragma unroll
  for (int i = 0; i < 4; ++i) {
    ra[i] = *(const short8*)(asrc + i * 16384);
    rb[i] = *(const short8*)(bsrc + i * 16384);
  }
  f32x4 acc[4][4];
  #pragma unroll
  for (int a = 0; a < 4; ++a)
    #pragma unroll
    for (int b = 0; b < 4; ++b) acc[a][b] = (f32x4){0.f, 0.f, 0.f, 0.f};
  for (int c = 0; c < 8; ++c) {
    __syncthreads();
    #pragma unroll
    for (int i = 0; i < 4; ++i) {
      *(short8*)(Ab + (i * 32 + srow) * 128 + dsw) = ra[i];
      *(short8*)(Bb + (i * 32 + srow) * 128 + dsw) = rb[i];
    }
    if (c < 7) {
      #pragma unroll
      for (int i = 0; i < 4; ++i) {
        ra[i] = *(const short8*)(asrc + i * 16384 + (c + 1) * 64);
        rb[i] = *(const short8*)(bsrc + i * 16384 + (c + 1) * 64);
      }
    }
    __syncthreads();
    #pragma unroll
    for (int ks = 0; ks < 2; ++ks) {
      const int so = (((ks << 2) | kg) ^ (lm & 7)) << 4;
      short8 af[4], bf[4];
      #pragma unroll
      for (int fr = 0; fr < 4; ++fr)
        af[fr] = *(const short8*)(Ab + (wr + fr * 16 + lm) * 128 + so);
      #pragma unroll
      for (int fc = 0; fc < 4; ++fc)
        bf[fc] = *(const short8*)(Bb + (wc + fc * 16 + lm) * 128 + so);
      #pragma unroll
      for (int fr = 0; fr < 4; ++fr)
        #pragma unroll
        for (int fc = 0; fc < 4; ++fc)
          acc[fr][fc] = __builtin_amdgcn_mfma_f32_16x16x32_bf16(af[fr], bf[fc], acc[fr][fc], 0, 0, 0);
    }
  }
  #pragma unroll
  for (int fr = 0; fr < 4; ++fr)
    #pragma unroll
    for (int fc = 0; fc < 4; ++fc)
      #pragma unroll
      for (int q = 0; q < 4; ++q) {
        int row = m0 + wr + fr * 16 + kg * 4 + q;
        int coln = n0 + wc + fc * 16 + lm;
        float v = acc[fr][fc][q];
        float vo = __shfl_xor(v, 1);
        if (!(lm & 1)) {
          unsigned int ud;
          asm("v_cvt_pk_bf16_f32 %0, %1, %2" : "=v"(ud) : "v"(v), "v"(vo));
          *(unsigned int*)(xg + (size_t)row * 1536 + coln) = ud;
        }
      }
}

// ---- level-loop pass (cooperative, custom barrier) ----
// grid 256 x 512 thr. rp = bi&31 (32 replicas), cg = bi>>5 (8 x 64 cols).
// bi%8 == rp&7 -> blocks sharing an A-tile sit on the SAME XCD (L2 reuse).
// Tile 256 rows x 64 cols; wave (wr=w>>1, wc=w&1) = 64 rows x 32 cols.
// LDS: Ah dbuf 2x32KB + B dbuf 2x24KB = 112KB; 1 barrier/chunk; 2-deep regs.
template <int PASS>
__launch_bounds__(512, 2)
__global__ void tree_pass(const unsigned short* __restrict__ xg,
                          unsigned short* __restrict__ Hcs,   // P0: Hdt; P1: Htd
                          unsigned short* __restrict__ Hout,  // P0: Hfd; P1: Htd
                          const unsigned short* __restrict__ wtU,
                          const unsigned short* __restrict__ zrow,
                          const float* __restrict__ bias,
                          const int* __restrict__ meta,
                          const int* __restrict__ pslot,
                          unsigned int* __restrict__ bar,
                          const unsigned short* __restrict__ Hfd,
                          const int* __restrict__ sched,
                          const int* __restrict__ root_index,
                          float* __restrict__ out) {
  extern __shared__ unsigned char lds[];
  unsigned char* Ah0 = lds;
  unsigned char* Ah1 = lds + 32768;
  unsigned char* Bw0 = lds + 65536;
  unsigned char* Bw1 = lds + 65536 + 24576;
  const int tid = threadIdx.x;
  const int bi  = blockIdx.x;
  const int rp = bi & 31;
  const int cg = bi >> 5;
  const int w = tid >> 6, l = tid & 63;
  const int wr = w >> 1, wc = w & 1;
  const int l31 = l & 31, lh = l >> 5;
  const int col = cg * 64 + wc * 32 + l31;
  const float br = bias[col], bz = bias[NH + col], bn = bias[2 * NH + col];

  // B staging: thread covers words j = tid + 512*i (i<3): 3 gates x 64 n x 128B
  const unsigned short* bsrc[3];
  int bdst[3];
  #pragma unroll
  for (int i = 0; i < 3; ++i) {
    int j = tid + 512 * i;
    int nrow = j >> 3, slot = j & 7;
    int gate = nrow >> 6, n = nrow & 63;
    bsrc[i] = wtU + (size_t)(gate * 512 + cg * 64 + n) * 512 + slot * 8;
    bdst[i] = nrow * 128 + ((slot * 16) ^ ((nrow & 7) << 4));
  }
  const int srow = tid >> 1;            // A staging: 2 thr/row, 64B halves
  const int sh64 = (tid & 1) * 64;
  const int half32 = (tid & 1) * 32;
  const int sdswz = (srow & 7) << 4;
  const int rsw = (l31 & 7) << 4;
  const int Dmax = meta[0];

  for (int p = 0; p <= Dmax; ++p) {
    const int d = PASS ? p : (Dmax - p);
    const int off_d = meta[1 + d];
    const int cnt_d = meta[257 + d];
    const int T = (cnt_d + 255) >> 8;
    for (int t = rp; t < T; t += 32) {
      const int g0 = off_d + t * 256;
      const int rows = min(256, cnt_d - t * 256);
      const int gg = g0 + min(srow, rows - 1);
      const unsigned short* shp;
      if (PASS == 0) {
        shp = Hcs + (size_t)gg * 512 + half32;
      } else {
        int ps = pslot[gg];
        shp = (ps >= 0 ? Hcs + (size_t)ps * 512 : zrow) + half32;
      }
      // prologue: load chunks cc0, cc1 into reg sets 0/1
      short8 sh0[4], sh1[4], sb0[3], sb1[3];
      const int cA = (cg + 1) & 7, cB = (cg + 2) & 7;
      #pragma unroll
      for (int jj = 0; jj < 4; ++jj) sh0[jj] = *(const short8*)(shp + cA * 64 + jj * 8);
      #pragma unroll
      for (int i = 0; i < 3; ++i) sb0[i] = *(const short8*)(bsrc[i] + cA * 64);
      #pragma unroll
      for (int jj = 0; jj < 4; ++jj) sh1[jj] = *(const short8*)(shp + cB * 64 + jj * 8);
      #pragma unroll
      for (int i = 0; i < 3; ++i) sb1[i] = *(const short8*)(bsrc[i] + cB * 64);
      __syncthreads();                   // prior tile's buffer readers done
      #pragma unroll
      for (int jj = 0; jj < 4; ++jj)
        *(short8*)(Ah0 + srow * 128 + ((sh64 + jj * 16) ^ sdswz)) = sh0[jj];
      #pragma unroll
      for (int i = 0; i < 3; ++i) *(short8*)(Bw0 + bdst[i]) = sb0[i];
      { const int c = (cg + 3) & 7;      // reload set0 <- cc2
        #pragma unroll
        for (int jj = 0; jj < 4; ++jj) sh0[jj] = *(const short8*)(shp + c * 64 + jj * 8);
        #pragma unroll
        for (int i = 0; i < 3; ++i) sb0[i] = *(const short8*)(bsrc[i] + c * 64);
      }
      __syncthreads();                   // buf0 visible

      f32x16 aR[2], aZ[2], aN[2];
      #pragma unroll
      for (int rf = 0; rf < 2; ++rf)
        #pragma unroll
        for (int e = 0; e < 16; ++e) { aR[rf][e] = 0.f; aZ[rf][e] = 0.f; aN[rf][e] = 0.f; }

      #pragma unroll
      for (int ci = 0; ci < 8; ++ci) {
        const unsigned char* Ar = (ci & 1) ? Ah1 : Ah0;
        const unsigned char* Br = (ci & 1) ? Bw1 : Bw0;
        #pragma unroll
        for (int ks = 0; ks < 4; ++ks) {
          const int kb = (ks * 32 + lh * 16) ^ rsw;
          short8 a0 = *(const short8*)(Ar + (wr * 64 + l31) * 128 + kb);
          short8 a1 = *(const short8*)(Ar + (wr * 64 + 32 + l31) * 128 + kb);
          short8 b0 = *(const short8*)(Br + (wc * 32 + l31) * 128 + kb);
          short8 b1 = *(const short8*)(Br + (64 + wc * 32 + l31) * 128 + kb);
          short8 b2 = *(const short8*)(Br + (128 + wc * 32 + l31) * 128 + kb);
          aR[0] = __builtin_amdgcn_mfma_f32_32x32x16_bf16(a0, b0, aR[0], 0, 0, 0);
          aR[1] = __builtin_amdgcn_mfma_f32_32x32x16_bf16(a1, b0, aR[1], 0, 0, 0);
          aZ[0] = __builtin_amdgcn_mfma_f32_32x32x16_bf16(a0, b1, aZ[0], 0, 0, 0);
          aZ[1] = __builtin_amdgcn_mfma_f32_32x32x16_bf16(a1, b1, aZ[1], 0, 0, 0);
          aN[0] = __builtin_amdgcn_mfma_f32_32x32x16_bf16(a0, b2, aN[0], 0, 0, 0);
          aN[1] = __builtin_amdgcn_mfma_f32_32x32x16_bf16(a1, b2, aN[1], 0, 0, 0);
        }
        if (ci < 7) {
          unsigned char* Aw = (ci & 1) ? Ah0 : Ah1;    // buf (ci+1)&1
          unsigned char* Bww = (ci & 1) ? Bw0 : Bw1;
          if ((ci & 1) == 0) {                          // write set1 (odd chunks)
            #pragma unroll
            for (int jj = 0; jj < 4; ++jj)
              *(short8*)(Aw + srow * 128 + ((sh64 + jj * 16) ^ sdswz)) = sh1[jj];
            #pragma unroll
            for (int i = 0; i < 3; ++i) *(short8*)(Bww + bdst[i]) = sb1[i];
            if (ci <= 4) {
              const int c = (cg + 4 + ci) & 7;
              #pragma unroll
              for (int jj = 0; jj < 4; ++jj) sh1[jj] = *(const short8*)(shp + c * 64 + jj * 8);
              #pragma unroll
              for (int i = 0; i < 3; ++i) sb1[i] = *(const short8*)(bsrc[i] + c * 64);
            }
          } else {                                      // write set0 (even chunks)
            #pragma unroll
            for (int jj = 0; jj < 4; ++jj)
              *(short8*)(Aw + srow * 128 + ((sh64 + jj * 16) ^ sdswz)) = sh0[jj];
            #pragma unroll
            for (int i = 0; i < 3; ++i) *(short8*)(Bww + bdst[i]) = sb0[i];
            if (ci <= 4) {
              const int c = (cg + 4 + ci) & 7;
              #pragma unroll
              for (int jj = 0; jj < 4; ++jj) sh0[jj] = *(const short8*)(shp + c * 64 + jj * 8);
              #pragma unroll
              for (int i = 0; i < 3; ++i) sb0[i] = *(const short8*)(bsrc[i] + c * 64);
            }
          }
          __syncthreads();
        }
      }
      // epilogue: buf1 holds chunk cg -> hprev from LDS; xg gathered per half.
      #pragma unroll
      for (int hf = 0; hf < 2; ++hf) {
        unsigned short xru[16], xzu[16], xnu[16];
        int psl[16];
        float hpv[16];
        #pragma unroll
        for (int reg = 0; reg < 16; ++reg) {
          const int row = wr * 64 + hf * 32 + (reg & 3) + 8 * (reg >> 2) + 4 * lh;
          const int gq = g0 + min(row, rows - 1);
          const size_t xb = (size_t)gq * 1536 + col;
          xru[reg] = xg[xb];
          xzu[reg] = xg[xb + 512];
          xnu[reg] = xg[xb + 1024];
          if (PASS == 0) psl[reg] = pslot[gq];
          hpv[reg] = bf2f(*(const unsigned short*)(
              Ah1 + row * 128 + ((2 * (wc * 32 + l31)) ^ ((row & 7) << 4))));
        }
        #pragma unroll
        for (int reg = 0; reg < 16; ++reg) {
          const int row = wr * 64 + hf * 32 + (reg & 3) + 8 * (reg >> 2) + 4 * lh;
          if (row < rows) {
            const int g = g0 + row;
            float rr = 1.f / (1.f + __expf(-(bf2f(xru[reg]) + br + aR[hf][reg])));
            float zz = 1.f / (1.f + __expf(-(bf2f(xzu[reg]) + bz + aZ[hf][reg])));
            float e2 = __expf(2.f * (bf2f(xnu[reg]) + bn + rr * aN[hf][reg]));
            float nn = (e2 - 1.f) / (e2 + 1.f);          // tanh
            float h = (1.f - zz) * nn + zz * hpv[reg];
            float ho = __shfl_xor(h, 1);
            if (!(l & 1)) {
              unsigned int ud;
              asm("v_cvt_pk_bf16_f32 %0, %1, %2" : "=v"(ud) : "v"(h), "v"(ho));
              *(unsigned int*)(Hout + (size_t)g * 512 + col) = ud;
              if (PASS == 0 && psl[reg] >= 0)
                atom_pk_bf16(Hcs + (size_t)psl[reg] * 512 + col, ud);
            }
          }
        }
      }
    }
    grid_bar(bar, (unsigned int)(p + 1));
  }

  // fused finalize (PASS1): compact Hfd/Htd -> out + root rows
  if (PASS == 1) {
    #pragma unroll
    for (int it = 0; it < 4; ++it) {
      const int g = bi * 128 + it * 32 + (tid >> 4);
      const int part = tid & 15;
      const int e = sched[g];
      const int b = e >> 8, node = e & 255;
      float* dst = out + ((size_t)b * NL + node) * 1024;
      const bool isroot = (node == root_index[b]);
      float* dst2 = out + (size_t)NB * NL * 1024 + (size_t)b * 1024;
      const unsigned short* s1 = Hfd + (size_t)g * 512 + part * 32;
      const unsigned short* s2 = Hout + (size_t)g * 512 + part * 32;
      #pragma unroll
      for (int half = 0; half < 2; ++half) {
        const unsigned short* s = half ? s2 : s1;
        const int o = half * 512 + part * 32;
        #pragma unroll
        for (int j = 0; j < 4; ++j) {
          short8 v = *(const short8*)(s + j * 8);
          f32x4 lo, hi;
          #pragma unroll
          for (int q = 0; q < 4; ++q) {
            lo[q] = bf2f((unsigned short)v[q]);
            hi[q] = bf2f((unsigned short)v[4 + q]);
          }
          __builtin_nontemporal_store(lo, (f32x4*)(dst + o + j * 8));
          __builtin_nontemporal_store(hi, (f32x4*)(dst + o + j * 8 + 4));
          if (isroot) {
            *(f32x4*)(dst2 + o + j * 8) = lo;
            *(f32x4*)(dst2 + o + j * 8 + 4) = hi;
          }
        }
      }
    }
  }
}

extern "C" void kernel_launch(void* const* d_in, const int* in_sizes, int n_in,
                              void* d_out, int out_size, void* d_ws, size_t ws_size,
                              hipStream_t stream) {
  (void)in_sizes; (void)n_in; (void)out_size; (void)ws_size;
  const float* emb      = (const float*)d_in[0];
  const int*   td_pidx  = (const int*)d_in[4];
  const float* td_pval  = (const float*)d_in[5];
  const int*   root_idx = (const int*)d_in[6];
  const float* dt_Wx    = (const float*)d_in[7];
  const float* dt_Uh    = (const float*)d_in[8];
  const float* dt_b     = (const float*)d_in[9];
  const float* td_Wx    = (const float*)d_in[10];
  const float* td_Uh    = (const float*)d_in[11];
  const float* td_b     = (const float*)d_in[12];
  float* out = (float*)d_out;

  unsigned short* wt   = (unsigned short*)d_ws;
  unsigned short* Xc   = wt + (size_t)4 * 1536 * 512;
  unsigned short* xg   = Xc + (size_t)NG * 512;
  unsigned short* Hdt  = xg + (size_t)NG * 1536;     // aliased as Htd in pass 1
  unsigned short* zrow = Hdt + (size_t)NG * 512;
  unsigned short* Hfd  = zrow + 512;
  int* sched = (int*)(Hfd + (size_t)NG * 512);
  int* meta  = sched + NG;
  int* gidx  = meta + 520;
  int* pslot = gidx + NG;
  unsigned int* bar0 = (unsigned int*)(pslot + NG);
  unsigned int* bar1 = bar0 + 64;

  (void)hipMemsetAsync(Hdt, 0, ((size_t)NG * 512 + 512) * 2, stream);  // Hdt + zrow
  (void)hipMemsetAsync(bar0, 0, 512, stream);
  prep_wt4<<<dim3(48, 16, 4), dim3(256), 0, stream>>>(dt_Wx, dt_Uh, td_Wx, td_Uh, wt);
  prep_sched<<<dim3(1), dim3(256), 0, stream>>>(td_pidx, td_pval, sched, meta, gidx, pslot);
  prep_xc<<<dim3(NG / 4), dim3(256), 0, stream>>>(emb, sched, Xc);

  (void)hipFuncSetAttribute((const void*)tree_pass<0>,
                            hipFuncAttributeMaxDynamicSharedMemorySize, 114688);
  (void)hipFuncSetAttribute((const void*)tree_pass<1>,
                            hipFuncAttributeMaxDynamicSharedMemorySize, 114688);

  // ---- DT (bottom-up) ----
  gemm_xg<<<dim3(256, 12), dim3(256), 0, stream>>>(Xc, wt, xg);
  {
    const unsigned short* wtU = wt + (size_t)1536 * 512;   // dt_Uh^T
    void* args[] = { (void*)&xg, (void*)&Hdt, (void*)&Hfd, (void*)&wtU, (void*)&zrow,
                     (void*)&dt_b, (void*)&meta, (void*)&pslot, (void*)&bar0,
                     (void*)&Hfd, (void*)&sched, (void*)&root_idx, (void*)&out };
    (void)hipLaunchCooperativeKernel((const void*)tree_pass<0>, dim3(NBLK), dim3(512),
                                     args, 114688u, stream);
  }
  // ---- TD (top-down), Htd aliases Hdt ----
  gemm_xg<<<dim3(256, 12), dim3(256), 0, stream>>>(Xc, wt + (size_t)2 * 1536 * 512, xg);
  {
    const unsigned short* wtU = wt + (size_t)3 * 1536 * 512;  // td_Uh^T
    void* args[] = { (void*)&xg, (void*)&Hdt, (void*)&Hdt, (void*)&wtU, (void*)&zrow,
                     (void*)&td_b, (void*)&meta, (void*)&pslot, (void*)&bar1,
                     (void*)&Hfd, (void*)&sched, (void*)&root_idx, (void*)&out };
    (void)hipLaunchCooperativeKernel((const void*)tree_pass<1>, dim3(NBLK), dim3(512),
                                     args, 114688u, stream);
  }
}

// Round 9
// 1658.962 us; speedup vs baseline: 2.3470x; 2.3470x over previous
//
#include <hip/hip_runtime.h>

// Tree-GRU encoder, round 9: fused DT+TD level loop with PER-LEVEL DATAFLOW
// FLAGS instead of grid barriers.
//  - done[pass][level] counters (units: rows x 32 colgroups). Producer tile:
//    epilogue atomics -> s_waitcnt vmcnt(0) -> syncthreads -> thread0 adds.
//    Consumer: thread0 spins (s_sleep) on the ONE dependency level, acquire
//    fence, go. Blocks with no tile at a level skip its wait -> passes and
//    col-groups pipeline instead of lock-stepping through 26 global barriers.
//  - ALL recurrent-state writes are global_atomic_pk_add_bf16 into zeroed
//    buffers (device-coherent point; cross-XCD-atomicity proven R4-R8), so
//    visibility costs vmcnt(0), not a bulk L2 writeback.
//  - out (129MB f32) untouched in the loop; fused tail finalize (nontemporal)
//    after fin counters reach NG*32. Loop working set ~140MB -> LLC-resident.
//  - XCD map: bi = cg*8 + pass*4 + rep -> bi%8 = pass*4+rep: the 32 blocks
//    sharing an A-row tile sit on ONE XCD; DT = XCD 0-3, TD = XCD 4-7.
//  - K-chunks rotated to end at this block's column chunk -> epilogue hprev
//    is an LDS read (no scattered global gathers).
//
// ws (~141 MB): wt 4x[1536][512] | Xc[NG][512] | Hdt|Htd|Hfd [NG][512] |
//               zrow[512] | ctr u32[520] | sched/meta/gidx/pslot

#define NL 256
#define NB 128
#define NH 512
#define NG (NB * NL)

typedef short short8 __attribute__((ext_vector_type(8)));
typedef float f32x4 __attribute__((ext_vector_type(4)));

__device__ __forceinline__ float bf2f(unsigned short u) {
  union { unsigned int i; float f; } c; c.i = ((unsigned int)u) << 16; return c.f;
}
__device__ __forceinline__ unsigned short f2bf(float f) {
  union { float f; unsigned int i; } c; c.f = f;
  return (unsigned short)((c.i + 0x7FFFu + ((c.i >> 16) & 1u)) >> 16);  // RNE
}
__device__ __forceinline__ short8 pk_bf16(f32x4 a, f32x4 b) {
  union { unsigned int u[4]; short8 s; } r;
  asm("v_cvt_pk_bf16_f32 %0, %1, %2" : "=v"(r.u[0]) : "v"(a[0]), "v"(a[1]));
  asm("v_cvt_pk_bf16_f32 %0, %1, %2" : "=v"(r.u[1]) : "v"(a[2]), "v"(a[3]));
  asm("v_cvt_pk_bf16_f32 %0, %1, %2" : "=v"(r.u[2]) : "v"(b[0]), "v"(b[1]));
  asm("v_cvt_pk_bf16_f32 %0, %1, %2" : "=v"(r.u[3]) : "v"(b[2]), "v"(b[3]));
  return r.s;
}
__device__ __forceinline__ void atom_pk_bf16(unsigned short* p, unsigned int ud) {
  asm volatile("global_atomic_pk_add_bf16 %0, %1, off" :: "v"((void*)p), "v"(ud) : "memory");
}

__device__ __forceinline__ void level_wait(unsigned int* c, unsigned int target) {
  if (threadIdx.x == 0) {
    while (__hip_atomic_load(c, __ATOMIC_RELAXED, __HIP_MEMORY_SCOPE_AGENT) < target)
      __builtin_amdgcn_s_sleep(8);
  }
  __syncthreads();
  __builtin_amdgcn_fence(__ATOMIC_ACQUIRE, "agent");
}

// ---- prep: 4 weight matrices [512][1536] f32 -> transposed [1536][512] bf16 ----
__global__ void prep_wt4(const float* __restrict__ w0, const float* __restrict__ w1,
                         const float* __restrict__ w2, const float* __restrict__ w3,
                         unsigned short* __restrict__ wt) {
  __shared__ float t[32][33];
  const float* w = blockIdx.z == 0 ? w0 : blockIdx.z == 1 ? w1 : blockIdx.z == 2 ? w2 : w3;
  unsigned short* dst = wt + (size_t)blockIdx.z * 1536 * 512;
  int n0 = blockIdx.x * 32, k0 = blockIdx.y * 32;
  int tx = threadIdx.x & 31, ty = threadIdx.x >> 5;
  #pragma unroll
  for (int i = 0; i < 4; ++i)
    t[ty + 8 * i][tx] = w[(size_t)(k0 + ty + 8 * i) * 1536 + n0 + tx];
  __syncthreads();
  #pragma unroll
  for (int i = 0; i < 4; ++i)
    dst[(size_t)(n0 + ty + 8 * i) * 512 + k0 + tx] = f2bf(t[tx][ty + 8 * i]);
}

// ---- prep: depths, level buckets, slots, parent slots (1 block, 256 thr) ----
__global__ void prep_sched(const int* __restrict__ td_pidx,
                           const float* __restrict__ td_pval,
                           int* __restrict__ sched, int* __restrict__ meta,
                           int* __restrict__ gidx, int* __restrict__ pslot) {
  __shared__ unsigned char dep[NB][NL];
  __shared__ unsigned short cnb[NB][256];
  __shared__ int cnt[256];
  __shared__ int off[257];
  __shared__ int dmax_s;
  const int tid = threadIdx.x;
  for (int j = tid; j < NB * 256; j += 256) ((unsigned short*)cnb)[j] = 0;
  if (tid == 0) dmax_s = 0;
  __syncthreads();
  if (tid < NB) {
    int b = tid, lmax = 0;
    for (int i = 0; i < NL; ++i) {
      float pv = td_pval[i * NB + b];
      int pi = td_pidx[i * NB + b];
      int d = (pv != 0.f) ? (int)dep[b][pi] + 1 : 0;   // head[i] < i
      dep[b][i] = (unsigned char)d;
      cnb[b][d]++;
      lmax = max(lmax, d);
    }
    atomicMax(&dmax_s, lmax);
  }
  __syncthreads();
  {
    int s = 0;
    for (int b = 0; b < NB; ++b) s += cnb[b][tid];
    cnt[tid] = s;
  }
  __syncthreads();
  if (tid == 0) {
    int s = 0;
    for (int d = 0; d < 256; ++d) { off[d] = s; s += cnt[d]; }
    off[256] = s;
  }
  __syncthreads();
  {
    int run = off[tid];
    for (int b = 0; b < NB; ++b) {
      int t = cnb[b][tid];
      cnb[b][tid] = (unsigned short)run;
      run += t;
    }
  }
  __syncthreads();
  if (tid < NB) {
    int b = tid;
    for (int i = 0; i < NL; ++i) {
      float pv = td_pval[i * NB + b];
      int pi = td_pidx[i * NB + b];
      int d = dep[b][i];
      int g = cnb[b][d]++;
      sched[g] = (b << 8) | i;
      gidx[b * NL + i] = g;
      pslot[g] = (pv != 0.f) ? gidx[b * NL + pi] : -1;
    }
  }
  if (tid == 0) meta[0] = dmax_s;
  __syncthreads();
  meta[1 + tid] = off[tid];
  meta[257 + tid] = cnt[tid];
}

// ---- prep: gather emb rows into slot order, f32 -> bf16 ----
__global__ void prep_xc(const float* __restrict__ emb, const int* __restrict__ sched,
                        unsigned short* __restrict__ Xc) {
  int g = blockIdx.x * 4 + (threadIdx.x >> 6);
  int lane = threadIdx.x & 63;
  int e = sched[g];
  int b = e >> 8, node = e & 255;
  const float* src = emb + ((size_t)node * NB + b) * 512 + lane * 8;
  f32x4 v0 = *(const f32x4*)src;
  f32x4 v1 = *(const f32x4*)(src + 4);
  *(short8*)(Xc + (size_t)g * 512 + lane * 8) = pk_bf16(v0, v1);
}

// ---- main fused kernel, flag-synced ----
// grid = 256 x 512 thr (8 waves, 1/CU). bi = cg*8 + pass*4 + rep.
// Block tile: 128 rows x 16 cols (cg of 32). Wave w owns rows [w*16,+16).
// LDS: weights 98304 | Xb 16K | Hb 16K = 131072.
__launch_bounds__(512, 2)
__global__ void tree_gru(const float* __restrict__ dt_b,
                         const float* __restrict__ td_b,
                         const unsigned short* __restrict__ wt,
                         const unsigned short* __restrict__ Xc,
                         unsigned short* __restrict__ Hdt,
                         unsigned short* __restrict__ Htd,
                         unsigned short* __restrict__ Hfd,
                         const unsigned short* __restrict__ zrow,
                         const int* __restrict__ meta,
                         const int* __restrict__ pslot,
                         unsigned int* __restrict__ ctr,
                         const int* __restrict__ sched,
                         const int* __restrict__ root_index,
                         float* __restrict__ out) {
  extern __shared__ unsigned char lds[];
  const int tid = threadIdx.x;
  const int bi  = blockIdx.x;
  const int cg   = bi >> 3;          // 0..31 col group (16 cols)
  const int pass = (bi >> 2) & 1;    // 0 = DT bottom-up, 1 = TD top-down
  const int rep  = bi & 3;           // row-tile replica
  const int w  = tid >> 6, l = tid & 63;
  const int lm = l & 15, kg = l >> 4;
  const int col = cg * 16 + lm;

  // stage weight slices: [mat(Wx,Uh)][gate(r,z,n)][n16][k512] bf16, XOR-swizzled
  for (int idx = tid; idx < 6144; idx += 512) {
    int k8  = idx & 63;
    int n   = (idx >> 6) & 15;
    int g   = (idx >> 10) % 3;
    int mat = idx / 3072;
    const unsigned short* src = wt + (size_t)(pass * 2 + mat) * (1536 * 512)
                                   + (size_t)(g * 512 + cg * 16 + n) * 512 + k8 * 8;
    short8 v = *(const short8*)src;
    int off = ((mat * 3 + g) * 16 + n) * 1024 + ((k8 * 16) ^ ((n & 7) << 4));
    *(short8*)(lds + off) = v;
  }
  unsigned char* Xb = lds + 98304;
  unsigned char* Hb = lds + 98304 + 16384;
  __syncthreads();

  const float* bias = pass ? td_b : dt_b;
  const float br = bias[col], bz = bias[NH + col], bn = bias[2 * NH + col];
  const int base_wr = (0 * 16 + lm) * 1024;
  const int base_wz = (1 * 16 + lm) * 1024;
  const int base_wn = (2 * 16 + lm) * 1024;
  const int base_ur = (3 * 16 + lm) * 1024;
  const int base_uz = (4 * 16 + lm) * 1024;
  const int base_un = (5 * 16 + lm) * 1024;
  const int wswz = (lm & 7) << 4;
  const int srow = tid >> 3, sslot = tid & 7;       // A-stage: 64 rows x 8 slots
  const int dsw = ((sslot ^ (srow & 7)) << 4);
  const int ck = cg >> 2;                           // chunk holding this block's cols
  const int ccol2 = 2 * ((cg & 3) * 16 + lm);       // byte offset of col in chunk row
  const int Dmax = meta[0];
  unsigned int* doneP = ctr + pass * 256;

  for (int p = 0; p <= Dmax; ++p) {
    const int d = pass ? p : (Dmax - p);
    const int off_d = meta[1 + d];
    const int cnt_d = meta[257 + d];
    const int T = (cnt_d + 127) >> 7;
    if (T <= rep) continue;                          // no tiles -> no wait
    const int dl = pass ? d - 1 : d + 1;             // dependency level
    if (dl >= 0 && dl <= Dmax)
      level_wait(doneP + dl, (unsigned int)meta[257 + dl] * 32u);
    for (int t = rep; t < T; t += 4) {
      const int g0 = off_d + t * 128;
      const int rows = min(128, cnt_d - t * 128);
      // staging sources: rows i*64+srow (clamped), 16B slot each — coalesced
      const unsigned short *sx[2], *sh[2];
      #pragma unroll
      for (int i = 0; i < 2; ++i) {
        int r = min(i * 64 + srow, rows - 1);
        int gg = g0 + r;
        sx[i] = Xc + (size_t)gg * 512 + sslot * 8;
        if (pass == 0) {
          sh[i] = Hdt + (size_t)gg * 512 + sslot * 8;
        } else {
          int ps = pslot[gg];
          sh[i] = (ps >= 0 ? Htd + (size_t)ps * 512 : zrow) + sslot * 8;
        }
      }
      const int c0 = (ck + 1) & 7;                   // rotated order ends at ck
      short8 rx0 = *(const short8*)(sx[0] + c0 * 64);
      short8 rx1 = *(const short8*)(sx[1] + c0 * 64);
      short8 rh0 = *(const short8*)(sh[0] + c0 * 64);
      short8 rh1 = *(const short8*)(sh[1] + c0 * 64);
      f32x4 aR = {0,0,0,0}, aZ = {0,0,0,0}, aXN = {0,0,0,0}, aHN = {0,0,0,0};
      #pragma unroll
      for (int ci = 0; ci < 8; ++ci) {
        const int c = (ck + 1 + ci) & 7;
        __syncthreads();                             // prev chunk consumed
        *(short8*)(Xb + (srow)      * 128 + dsw) = rx0;
        *(short8*)(Xb + (64 + srow) * 128 + dsw) = rx1;
        *(short8*)(Hb + (srow)      * 128 + dsw) = rh0;
        *(short8*)(Hb + (64 + srow) * 128 + dsw) = rh1;
        if (ci < 7) {
          const int cn = (ck + 2 + ci) & 7;
          rx0 = *(const short8*)(sx[0] + cn * 64);
          rx1 = *(const short8*)(sx[1] + cn * 64);
          rh0 = *(const short8*)(sh[0] + cn * 64);
          rh1 = *(const short8*)(sh[1] + cn * 64);
        }
        __syncthreads();                             // chunk visible
        #pragma unroll
        for (int ks = 0; ks < 2; ++ks) {
          const int so = (((ks << 2) | kg) ^ (lm & 7)) << 4;
          const int arow = w * 16 + lm;
          short8 ax = *(const short8*)(Xb + arow * 128 + so);
          short8 ah = *(const short8*)(Hb + arow * 128 + so);
          const int kb = (c * 128 + ks * 64 + kg * 16) ^ wswz;
          short8 bwr = *(const short8*)(lds + base_wr + kb);
          short8 bwz = *(const short8*)(lds + base_wz + kb);
          short8 bwn = *(const short8*)(lds + base_wn + kb);
          short8 bur = *(const short8*)(lds + base_ur + kb);
          short8 buz = *(const short8*)(lds + base_uz + kb);
          short8 bun = *(const short8*)(lds + base_un + kb);
          aR  = __builtin_amdgcn_mfma_f32_16x16x32_bf16(ax, bwr, aR, 0, 0, 0);
          aZ  = __builtin_amdgcn_mfma_f32_16x16x32_bf16(ax, bwz, aZ, 0, 0, 0);
          aXN = __builtin_amdgcn_mfma_f32_16x16x32_bf16(ax, bwn, aXN, 0, 0, 0);
          aR  = __builtin_amdgcn_mfma_f32_16x16x32_bf16(ah, bur, aR, 0, 0, 0);
          aZ  = __builtin_amdgcn_mfma_f32_16x16x32_bf16(ah, buz, aZ, 0, 0, 0);
          aHN = __builtin_amdgcn_mfma_f32_16x16x32_bf16(ah, bun, aHN, 0, 0, 0);
        }
      }
      // epilogue: Hb holds chunk ck -> hprev from LDS. Row = w*16+kg*4+q, col=lm.
      #pragma unroll
      for (int q = 0; q < 4; ++q) {
        const int r = w * 16 + kg * 4 + q;
        if (r >= rows) continue;
        const int g = g0 + r;
        const float hprev = bf2f(*(const unsigned short*)(
            Hb + r * 128 + (ccol2 ^ ((r & 7) << 4))));
        float rr = 1.f / (1.f + __expf(-(aR[q] + br)));
        float zz = 1.f / (1.f + __expf(-(aZ[q] + bz)));
        float e2 = __expf(2.f * (aXN[q] + bn + rr * aHN[q]));
        float nn = (e2 - 1.f) / (e2 + 1.f);          // tanh
        float h = (1.f - zz) * nn + zz * hprev;
        float ho = __shfl_xor(h, 1);
        if (!(lm & 1)) {
          unsigned int ud;
          asm("v_cvt_pk_bf16_f32 %0, %1, %2" : "=v"(ud) : "v"(h), "v"(ho));
          if (pass == 0) {
            atom_pk_bf16(Hfd + (size_t)g * 512 + col, ud);   // buffers zeroed
            int ps = pslot[g];
            if (ps >= 0) atom_pk_bf16(Hdt + (size_t)ps * 512 + col, ud);
          } else {
            atom_pk_bf16(Htd + (size_t)g * 512 + col, ud);
          }
        }
      }
      // producer commit: atomics ack'd at coherent point, then count rows
      asm volatile("s_waitcnt vmcnt(0)" ::: "memory");
      __syncthreads();
      if (tid == 0) {
        __hip_atomic_fetch_add(doneP + d, (unsigned int)rows,
                               __ATOMIC_RELAXED, __HIP_MEMORY_SCOPE_AGENT);
        __hip_atomic_fetch_add(ctr + 512 + pass, (unsigned int)rows,
                               __ATOMIC_RELAXED, __HIP_MEMORY_SCOPE_AGENT);
      }
    }
  }

  // tail finalize: wait both passes fully done, stream compact -> out (f32)
  level_wait(ctr + 512, (unsigned int)NG * 32u);
  level_wait(ctr + 513, (unsigned int)NG * 32u);
  #pragma unroll
  for (int it = 0; it < 4; ++it) {
    const int g = bi * 128 + it * 32 + (tid >> 4);
    const int part = tid & 15;
    const int e = sched[g];
    const int b = e >> 8, node = e & 255;
    float* dst = out + ((size_t)b * NL + node) * 1024;
    const bool isroot = (node == root_index[b]);
    float* dst2 = out + (size_t)NB * NL * 1024 + (size_t)b * 1024;
    const unsigned short* s1 = Hfd + (size_t)g * 512 + part * 32;
    const unsigned short* s2 = Htd + (size_t)g * 512 + part * 32;
    #pragma unroll
    for (int half = 0; half < 2; ++half) {
      const unsigned short* s = half ? s2 : s1;
      const int o = half * 512 + part * 32;
      #pragma unroll
      for (int j = 0; j < 4; ++j) {
        short8 v = *(const short8*)(s + j * 8);
        f32x4 lo, hi;
        #pragma unroll
        for (int q = 0; q < 4; ++q) {
          lo[q] = bf2f((unsigned short)v[q]);
          hi[q] = bf2f((unsigned short)v[4 + q]);
        }
        __builtin_nontemporal_store(lo, (f32x4*)(dst + o + j * 8));
        __builtin_nontemporal_store(hi, (f32x4*)(dst + o + j * 8 + 4));
        if (isroot) {
          *(f32x4*)(dst2 + o + j * 8) = lo;
          *(f32x4*)(dst2 + o + j * 8 + 4) = hi;
        }
      }
    }
  }
}

extern "C" void kernel_launch(void* const* d_in, const int* in_sizes, int n_in,
                              void* d_out, int out_size, void* d_ws, size_t ws_size,
                              hipStream_t stream) {
  (void)in_sizes; (void)n_in; (void)out_size; (void)ws_size;
  const float* emb      = (const float*)d_in[0];
  const int*   td_pidx  = (const int*)d_in[4];
  const float* td_pval  = (const float*)d_in[5];
  const int*   root_idx = (const int*)d_in[6];
  const float* dt_Wx    = (const float*)d_in[7];
  const float* dt_Uh    = (const float*)d_in[8];
  const float* dt_b     = (const float*)d_in[9];
  const float* td_Wx    = (const float*)d_in[10];
  const float* td_Uh    = (const float*)d_in[11];
  const float* td_b     = (const float*)d_in[12];
  float* out = (float*)d_out;

  unsigned short* wt   = (unsigned short*)d_ws;
  unsigned short* Xc   = wt + (size_t)4 * 1536 * 512;
  unsigned short* Hdt  = Xc + (size_t)NG * NH;      // ---- zeroed region start
  unsigned short* Htd  = Hdt + (size_t)NG * NH;
  unsigned short* Hfd  = Htd + (size_t)NG * NH;
  unsigned short* zrow = Hfd + (size_t)NG * NH;
  unsigned int*   ctr  = (unsigned int*)(zrow + NH); // 520 u32 ---- zeroed end
  int* sched = (int*)(ctr + 520);
  int* meta  = sched + NG;
  int* gidx  = meta + 520;
  int* pslot = gidx + NG;

  const size_t zbytes = (size_t)3 * NG * NH * 2 + NH * 2 + 520 * 4;
  (void)hipMemsetAsync(Hdt, 0, zbytes, stream);     // Hdt,Htd,Hfd,zrow,ctr
  prep_wt4<<<dim3(48, 16, 4), dim3(256), 0, stream>>>(dt_Wx, dt_Uh, td_Wx, td_Uh, wt);
  prep_sched<<<dim3(1), dim3(256), 0, stream>>>(td_pidx, td_pval, sched, meta, gidx, pslot);
  prep_xc<<<dim3(NG / 4), dim3(256), 0, stream>>>(emb, sched, Xc);

  (void)hipFuncSetAttribute((const void*)tree_gru,
                            hipFuncAttributeMaxDynamicSharedMemorySize, 131072);

  void* args[] = {
    (void*)&dt_b, (void*)&td_b, (void*)&wt, (void*)&Xc, (void*)&Hdt, (void*)&Htd,
    (void*)&Hfd, (void*)&zrow, (void*)&meta, (void*)&pslot, (void*)&ctr,
    (void*)&sched, (void*)&root_idx, (void*)&out
  };
  (void)hipLaunchCooperativeKernel((const void*)tree_gru, dim3(256), dim3(512),
                                   args, 131072u, stream);
}